// Round 1
// baseline (5922.280 us; speedup 1.0000x reference)
//
#include <hip/hip_runtime.h>
#include <hip/hip_bf16.h>
#include <math.h>

// Problem constants
#define NB    1024      // batch rows == scan steps
#define SEQ   600
#define EDIM  300
#define HDIM  256
#define DIN   903       // 3*E + 3
#define GDIM  1024      // 4*H

// ---------------------------------------------------------------------------
// Kernel 1: conv — per row: 3 segment means of gathered embeddings + 3 cosines
// X[row][0:300]=st, [300]=cos(st,su), [301:601]=su, [601]=cos(su,ju),
// [602:902]=ju, [902]=cos(st,ju)
// ---------------------------------------------------------------------------
__global__ __launch_bounds__(256) void conv_kernel(const int* __restrict__ x,
                                                   const float* __restrict__ emb,
                                                   float* __restrict__ X) {
    const int row = blockIdx.x;
    const int tid = threadIdx.x;
    const int* xr = x + (size_t)row * SEQ;

    __shared__ float seg[3][EDIM];
    __shared__ float scnt[3];
    __shared__ float reds[6];   // nt2, nu2, nj2, tu, uj, tj
    __shared__ float coss[3];

    if (tid < 6) reds[tid] = 0.f;
    if (tid < 3) scnt[tid] = 0.f;
    __syncthreads();

    // counts of nonzero tokens per segment
    {
        int c0 = 0, c1 = 0, c2 = 0;
        for (int t = tid; t < 200; t += 256) {
            c0 += (xr[t]       != 0);
            c1 += (xr[200 + t] != 0);
            c2 += (xr[400 + t] != 0);
        }
        float f0 = (float)c0, f1 = (float)c1, f2 = (float)c2;
        #pragma unroll
        for (int m = 1; m < 64; m <<= 1) {
            f0 += __shfl_xor(f0, m);
            f1 += __shfl_xor(f1, m);
            f2 += __shfl_xor(f2, m);
        }
        if ((tid & 63) == 0) {
            atomicAdd(&scnt[0], f0);
            atomicAdd(&scnt[1], f1);
            atomicAdd(&scnt[2], f2);
        }
    }
    __syncthreads();

    const float inv0 = 1.f / scnt[0], inv1 = 1.f / scnt[1], inv2 = 1.f / scnt[2];

    // segment sums (gather) -> means
    for (int d = tid; d < EDIM; d += 256) {
        float a0 = 0.f, a1 = 0.f, a2 = 0.f;
        for (int t = 0; t < 200; t++) {
            a0 += emb[(size_t)xr[t]       * EDIM + d];
            a1 += emb[(size_t)xr[200 + t] * EDIM + d];
            a2 += emb[(size_t)xr[400 + t] * EDIM + d];
        }
        seg[0][d] = a0 * inv0;
        seg[1][d] = a1 * inv1;
        seg[2][d] = a2 * inv2;
    }
    __syncthreads();

    // dots and norms over the means
    {
        float p0 = 0, p1 = 0, p2 = 0, p3 = 0, p4 = 0, p5 = 0;
        for (int d = tid; d < EDIM; d += 256) {
            float a = seg[0][d], b = seg[1][d], c = seg[2][d];
            p0 += a * a; p1 += b * b; p2 += c * c;
            p3 += a * b; p4 += b * c; p5 += a * c;
        }
        #pragma unroll
        for (int m = 1; m < 64; m <<= 1) {
            p0 += __shfl_xor(p0, m); p1 += __shfl_xor(p1, m);
            p2 += __shfl_xor(p2, m); p3 += __shfl_xor(p3, m);
            p4 += __shfl_xor(p4, m); p5 += __shfl_xor(p5, m);
        }
        if ((tid & 63) == 0) {
            atomicAdd(&reds[0], p0); atomicAdd(&reds[1], p1);
            atomicAdd(&reds[2], p2); atomicAdd(&reds[3], p3);
            atomicAdd(&reds[4], p4); atomicAdd(&reds[5], p5);
        }
    }
    __syncthreads();
    if (tid == 0) {
        float nt = fmaxf(sqrtf(reds[0]), 1e-8f);
        float nu = fmaxf(sqrtf(reds[1]), 1e-8f);
        float nj = fmaxf(sqrtf(reds[2]), 1e-8f);
        coss[0] = reds[3] / (nt * nu);
        coss[1] = reds[4] / (nu * nj);
        coss[2] = reds[5] / (nt * nj);
    }
    __syncthreads();

    float* Xr = X + (size_t)row * DIN;
    for (int col = tid; col < DIN; col += 256) {
        float v;
        if      (col < 300)  v = seg[0][col];
        else if (col == 300) v = coss[0];
        else if (col < 601)  v = seg[1][col - 301];
        else if (col == 601) v = coss[1];
        else if (col < 902)  v = seg[2][col - 602];
        else                 v = coss[2];
        Xr[col] = v;
    }
}

// ---------------------------------------------------------------------------
// Kernel 2: GEMM  C[1024][1024] = A[1024][K] * B[1024][K]^T + bias1 + bias2
// 64x64 tile per 256-thread block, 4x4 micro-tile per thread.
// ---------------------------------------------------------------------------
__global__ __launch_bounds__(256) void gemm_bias(const float* __restrict__ A,
                                                 const float* __restrict__ Bm,
                                                 const float* __restrict__ bias1,
                                                 const float* __restrict__ bias2,
                                                 float* __restrict__ C, int K) {
    __shared__ float As[16][68];
    __shared__ float Bs[16][68];
    const int tid = threadIdx.x;
    const int tx = tid & 15, ty = tid >> 4;
    const int m0 = blockIdx.y * 64, n0 = blockIdx.x * 64;

    float acc[4][4] = {};
    for (int k0 = 0; k0 < K; k0 += 16) {
        #pragma unroll
        for (int i = 0; i < 4; i++) {
            int e  = tid + i * 256;
            int rr = e >> 4, kk = e & 15;
            int k  = k0 + kk;
            As[kk][rr] = (k < K) ? A[(size_t)(m0 + rr) * K + k] : 0.f;
            Bs[kk][rr] = (k < K) ? Bm[(size_t)(n0 + rr) * K + k] : 0.f;
        }
        __syncthreads();
        #pragma unroll
        for (int kk = 0; kk < 16; kk++) {
            float a[4], b[4];
            #pragma unroll
            for (int i = 0; i < 4; i++) { a[i] = As[kk][ty * 4 + i]; b[i] = Bs[kk][tx * 4 + i]; }
            #pragma unroll
            for (int i = 0; i < 4; i++)
                #pragma unroll
                for (int j = 0; j < 4; j++)
                    acc[i][j] += a[i] * b[j];
        }
        __syncthreads();
    }
    #pragma unroll
    for (int i = 0; i < 4; i++) {
        int m = m0 + ty * 4 + i;
        #pragma unroll
        for (int j = 0; j < 4; j++) {
            int n = n0 + tx * 4 + j;
            C[(size_t)m * GDIM + n] = acc[i][j] + bias1[n] + bias2[n];
        }
    }
}

// ---------------------------------------------------------------------------
// Kernel 3: sequential LSTM layer. 8 workgroups x 512 threads.
// WG w owns h-slice [w*32, w*32+32) and the 4 corresponding gate-row groups
// (i,f,g,o), i.e. 128 rows of W_hh kept in registers (64 fp32/thread).
// h broadcast each step through a device-scope atomic mailbox (parity
// double-buffered) + per-WG step flags.
// ---------------------------------------------------------------------------
__global__ __launch_bounds__(512) void lstm_seq(const float* __restrict__ G,
                                                const float* __restrict__ Whh,
                                                const float* __restrict__ h0,
                                                const float* __restrict__ c0,
                                                float* __restrict__ ys,
                                                float* __restrict__ hn,
                                                float* __restrict__ cn,
                                                float* mail,   // [2][256]
                                                int*   flags)  // [8]
{
    const int w    = blockIdx.x;        // 0..7
    const int tid  = threadIdx.x;       // 0..511
    const int q    = tid & 3;           // k-quarter
    const int r    = tid >> 2;          // 0..127 local gate row
    const int chunk = r >> 5;           // 0..3 (i,f,g,o)
    const int elem  = r & 31;
    const int grow  = chunk * 256 + w * 32 + elem;  // global gate row

    __shared__ __align__(16) float h_lds[HDIM];
    __shared__ float gate_lds[128];
    __shared__ float c_lds[32];

    // load this thread's 64 weights into registers
    float wreg[64];
    {
        const float4* wr4 = (const float4*)(Whh + (size_t)grow * HDIM + q * 64);
        #pragma unroll
        for (int j = 0; j < 16; j++) {
            float4 v = wr4[j];
            wreg[4 * j + 0] = v.x; wreg[4 * j + 1] = v.y;
            wreg[4 * j + 2] = v.z; wreg[4 * j + 3] = v.w;
        }
    }
    if (tid < HDIM) h_lds[tid] = h0[tid];
    if (tid < 32)   c_lds[tid] = c0[w * 32 + tid];
    __syncthreads();

    for (int t = 0; t < NB; t++) {
        // issue G-row load early so it overlaps the spin
        float gval = 0.f;
        if (q == 0) gval = G[(size_t)t * GDIM + grow];

        if (t > 0) {
            if (tid < 8) {
                int guard = 0;
                while (__hip_atomic_load(&flags[tid], __ATOMIC_ACQUIRE,
                                         __HIP_MEMORY_SCOPE_AGENT) < t) {
                    if (++guard > (1 << 22)) break;   // fail loudly, don't hang
                }
            }
            __syncthreads();
            const float* mslot = mail + ((t - 1) & 1) * HDIM;
            if (tid < HDIM)
                h_lds[tid] = __hip_atomic_load(&mslot[tid], __ATOMIC_RELAXED,
                                               __HIP_MEMORY_SCOPE_AGENT);
            __syncthreads();
        }

        // matvec: this thread's quarter-row dot
        float acc = 0.f;
        {
            const float4* h4 = ((const float4*)h_lds) + q * 16;
            #pragma unroll
            for (int j = 0; j < 16; j++) {
                float4 hv = h4[j];
                acc += hv.x * wreg[4 * j + 0] + hv.y * wreg[4 * j + 1]
                     + hv.z * wreg[4 * j + 2] + hv.w * wreg[4 * j + 3];
            }
        }
        acc += __shfl_xor(acc, 1);
        acc += __shfl_xor(acc, 2);
        if (q == 0) gate_lds[r] = acc + gval;
        __syncthreads();

        if (tid < 32) {
            float gi = gate_lds[tid];
            float gf = gate_lds[32 + tid];
            float gg = gate_lds[64 + tid];
            float go = gate_lds[96 + tid];
            float ig = 1.f / (1.f + expf(-gi));
            float fg = 1.f / (1.f + expf(-gf));
            float og = 1.f / (1.f + expf(-go));
            float gv = tanhf(gg);
            float c  = fg * c_lds[tid] + ig * gv;
            c_lds[tid] = c;
            float h  = og * tanhf(c);
            ys[(size_t)t * HDIM + w * 32 + tid] = h;
            __hip_atomic_store(&mail[(t & 1) * HDIM + w * 32 + tid], h,
                               __ATOMIC_RELAXED, __HIP_MEMORY_SCOPE_AGENT);
            if (t == NB - 1) {
                hn[w * 32 + tid] = h;
                cn[w * 32 + tid] = c;
            }
        }
        __syncthreads();   // all mailbox stores drained (waitcnt before barrier)
        if (tid == 0)
            __hip_atomic_store(&flags[w], t + 1, __ATOMIC_RELEASE,
                               __HIP_MEMORY_SCOPE_AGENT);
    }
}

// ---------------------------------------------------------------------------
// Kernel 4: fc head — sig_out[t] = sigmoid(dot(ys2[t], fc_w) + fc_b)
// one wave per row
// ---------------------------------------------------------------------------
__global__ __launch_bounds__(256) void fc_kernel(const float* __restrict__ ys2,
                                                 const float* __restrict__ fc_w,
                                                 const float* __restrict__ fc_b,
                                                 float* __restrict__ out) {
    const int row  = blockIdx.x * 4 + (threadIdx.x >> 6);
    const int lane = threadIdx.x & 63;
    float4 y = ((const float4*)(ys2 + (size_t)row * HDIM))[lane];
    float4 wv = ((const float4*)fc_w)[lane];
    float d = y.x * wv.x + y.y * wv.y + y.z * wv.z + y.w * wv.w;
    #pragma unroll
    for (int m = 1; m < 64; m <<= 1) d += __shfl_xor(d, m);
    if (lane == 0) out[row] = 1.f / (1.f + expf(-(d + fc_b[0])));
}

// ---------------------------------------------------------------------------
extern "C" void kernel_launch(void* const* d_in, const int* in_sizes, int n_in,
                              void* d_out, int out_size, void* d_ws, size_t ws_size,
                              hipStream_t stream) {
    const int*   x     = (const int*)  d_in[0];
    const float* h0    = (const float*)d_in[1];   // (2,1,256)
    const float* c0    = (const float*)d_in[2];
    const float* emb   = (const float*)d_in[3];
    const float* w_ih0 = (const float*)d_in[4];
    const float* w_hh0 = (const float*)d_in[5];
    const float* b_ih0 = (const float*)d_in[6];
    const float* b_hh0 = (const float*)d_in[7];
    const float* w_ih1 = (const float*)d_in[8];
    const float* w_hh1 = (const float*)d_in[9];
    const float* b_ih1 = (const float*)d_in[10];
    const float* b_hh1 = (const float*)d_in[11];
    const float* fc_w  = (const float*)d_in[12];
    const float* fc_b  = (const float*)d_in[13];
    float* out = (float*)d_out;

    // workspace layout (floats)
    float* X     = (float*)d_ws;                 // 1024*903
    float* G     = X + (size_t)NB * DIN;         // 1024*1024 (reused for both layers)
    float* ys1   = G + (size_t)NB * GDIM;        // 1024*256
    float* ys2   = ys1 + (size_t)NB * HDIM;      // 1024*256
    float* mail0 = ys2 + (size_t)NB * HDIM;      // 2*256
    float* mail1 = mail0 + 2 * HDIM;             // 2*256
    int*   flags = (int*)(mail1 + 2 * HDIM);     // 16 ints (8 per layer)

    hipMemsetAsync(flags, 0, 16 * sizeof(int), stream);

    conv_kernel<<<NB, 256, 0, stream>>>(x, emb, X);

    gemm_bias<<<dim3(16, 16), 256, 0, stream>>>(X, w_ih0, b_ih0, b_hh0, G, DIN);

    lstm_seq<<<8, 512, 0, stream>>>(G, w_hh0, h0, c0, ys1,
                                    out + 1024, out + 1536, mail0, flags);

    gemm_bias<<<dim3(16, 16), 256, 0, stream>>>(ys1, w_ih1, b_ih1, b_hh1, G, HDIM);

    lstm_seq<<<8, 512, 0, stream>>>(G, w_hh1, h0 + HDIM, c0 + HDIM, ys2,
                                    out + 1024 + HDIM, out + 1536 + HDIM,
                                    mail1, flags + 8);

    fc_kernel<<<NB / 4, 256, 0, stream>>>(ys2, fc_w, fc_b, out);
}

// Round 2
// 3575.179 us; speedup vs baseline: 1.6565x; 1.6565x over previous
//
#include <hip/hip_runtime.h>
#include <hip/hip_bf16.h>
#include <math.h>

// Problem constants
#define NB    1024      // batch rows == scan steps
#define SEQ   600
#define EDIM  300
#define HDIM  256
#define DIN   903       // 3*E + 3
#define GDIM  1024      // 4*H

// ---------------------------------------------------------------------------
// Kernel 1: conv — per row: 3 segment means of gathered embeddings + 3 cosines
// ---------------------------------------------------------------------------
__global__ __launch_bounds__(256) void conv_kernel(const int* __restrict__ x,
                                                   const float* __restrict__ emb,
                                                   float* __restrict__ X) {
    const int row = blockIdx.x;
    const int tid = threadIdx.x;
    const int* xr = x + (size_t)row * SEQ;

    __shared__ float seg[3][EDIM];
    __shared__ float scnt[3];
    __shared__ float reds[6];
    __shared__ float coss[3];

    if (tid < 6) reds[tid] = 0.f;
    if (tid < 3) scnt[tid] = 0.f;
    __syncthreads();

    {
        int c0 = 0, c1 = 0, c2 = 0;
        for (int t = tid; t < 200; t += 256) {
            c0 += (xr[t]       != 0);
            c1 += (xr[200 + t] != 0);
            c2 += (xr[400 + t] != 0);
        }
        float f0 = (float)c0, f1 = (float)c1, f2 = (float)c2;
        #pragma unroll
        for (int m = 1; m < 64; m <<= 1) {
            f0 += __shfl_xor(f0, m);
            f1 += __shfl_xor(f1, m);
            f2 += __shfl_xor(f2, m);
        }
        if ((tid & 63) == 0) {
            atomicAdd(&scnt[0], f0);
            atomicAdd(&scnt[1], f1);
            atomicAdd(&scnt[2], f2);
        }
    }
    __syncthreads();

    const float inv0 = 1.f / scnt[0], inv1 = 1.f / scnt[1], inv2 = 1.f / scnt[2];

    for (int d = tid; d < EDIM; d += 256) {
        float a0 = 0.f, a1 = 0.f, a2 = 0.f;
        for (int t = 0; t < 200; t++) {
            a0 += emb[(size_t)xr[t]       * EDIM + d];
            a1 += emb[(size_t)xr[200 + t] * EDIM + d];
            a2 += emb[(size_t)xr[400 + t] * EDIM + d];
        }
        seg[0][d] = a0 * inv0;
        seg[1][d] = a1 * inv1;
        seg[2][d] = a2 * inv2;
    }
    __syncthreads();

    {
        float p0 = 0, p1 = 0, p2 = 0, p3 = 0, p4 = 0, p5 = 0;
        for (int d = tid; d < EDIM; d += 256) {
            float a = seg[0][d], b = seg[1][d], c = seg[2][d];
            p0 += a * a; p1 += b * b; p2 += c * c;
            p3 += a * b; p4 += b * c; p5 += a * c;
        }
        #pragma unroll
        for (int m = 1; m < 64; m <<= 1) {
            p0 += __shfl_xor(p0, m); p1 += __shfl_xor(p1, m);
            p2 += __shfl_xor(p2, m); p3 += __shfl_xor(p3, m);
            p4 += __shfl_xor(p4, m); p5 += __shfl_xor(p5, m);
        }
        if ((tid & 63) == 0) {
            atomicAdd(&reds[0], p0); atomicAdd(&reds[1], p1);
            atomicAdd(&reds[2], p2); atomicAdd(&reds[3], p3);
            atomicAdd(&reds[4], p4); atomicAdd(&reds[5], p5);
        }
    }
    __syncthreads();
    if (tid == 0) {
        float nt = fmaxf(sqrtf(reds[0]), 1e-8f);
        float nu = fmaxf(sqrtf(reds[1]), 1e-8f);
        float nj = fmaxf(sqrtf(reds[2]), 1e-8f);
        coss[0] = reds[3] / (nt * nu);
        coss[1] = reds[4] / (nu * nj);
        coss[2] = reds[5] / (nt * nj);
    }
    __syncthreads();

    float* Xr = X + (size_t)row * DIN;
    for (int col = tid; col < DIN; col += 256) {
        float v;
        if      (col < 300)  v = seg[0][col];
        else if (col == 300) v = coss[0];
        else if (col < 601)  v = seg[1][col - 301];
        else if (col == 601) v = coss[1];
        else if (col < 902)  v = seg[2][col - 602];
        else                 v = coss[2];
        Xr[col] = v;
    }
}

// ---------------------------------------------------------------------------
// Kernel 2: GEMM  C[1024][1024] = A[1024][K] * B[1024][K]^T + bias1 + bias2
// ---------------------------------------------------------------------------
__global__ __launch_bounds__(256) void gemm_bias(const float* __restrict__ A,
                                                 const float* __restrict__ Bm,
                                                 const float* __restrict__ bias1,
                                                 const float* __restrict__ bias2,
                                                 float* __restrict__ C, int K) {
    __shared__ float As[16][68];
    __shared__ float Bs[16][68];
    const int tid = threadIdx.x;
    const int tx = tid & 15, ty = tid >> 4;
    const int m0 = blockIdx.y * 64, n0 = blockIdx.x * 64;

    float acc[4][4] = {};
    for (int k0 = 0; k0 < K; k0 += 16) {
        #pragma unroll
        for (int i = 0; i < 4; i++) {
            int e  = tid + i * 256;
            int rr = e >> 4, kk = e & 15;
            int k  = k0 + kk;
            As[kk][rr] = (k < K) ? A[(size_t)(m0 + rr) * K + k] : 0.f;
            Bs[kk][rr] = (k < K) ? Bm[(size_t)(n0 + rr) * K + k] : 0.f;
        }
        __syncthreads();
        #pragma unroll
        for (int kk = 0; kk < 16; kk++) {
            float a[4], b[4];
            #pragma unroll
            for (int i = 0; i < 4; i++) { a[i] = As[kk][ty * 4 + i]; b[i] = Bs[kk][tx * 4 + i]; }
            #pragma unroll
            for (int i = 0; i < 4; i++)
                #pragma unroll
                for (int j = 0; j < 4; j++)
                    acc[i][j] += a[i] * b[j];
        }
        __syncthreads();
    }
    #pragma unroll
    for (int i = 0; i < 4; i++) {
        int m = m0 + ty * 4 + i;
        #pragma unroll
        for (int j = 0; j < 4; j++) {
            int n = n0 + tx * 4 + j;
            C[(size_t)m * GDIM + n] = acc[i][j] + bias1[n] + bias2[n];
        }
    }
}

// ---------------------------------------------------------------------------
// Kernel 3: fused 2-layer sequential LSTM. 16 WGs x 1024 threads.
// WGs 0..7  = layer 1: gates from precomputed G1 + Whh0·h1.
// WGs 8..15 = layer 2: gates from Wih1·ys1[t] (on the fly) + Whh1·h2 + biases.
// h exchange: write-once rows ys[t][256] (pre-filled 0xFFFFFFFF = NaN);
// consumers poll their own dword until pattern != 0xFFFFFFFF. No flags,
// no release fences; ys rows double as the layer outputs.
// Thread map: q = tid&7 (32-wide chunk of the 256 dim), r = tid>>3 (gate row
// 0..127 local); global gate row = (r>>5)*256 + w*32 + (r&31).
// ---------------------------------------------------------------------------
__global__ __launch_bounds__(1024) void lstm_fused(
    const float* __restrict__ G1,
    const float* __restrict__ Whh0,
    const float* __restrict__ Wih1,
    const float* __restrict__ Whh1,
    const float* __restrict__ b_ih1,
    const float* __restrict__ b_hh1,
    const float* __restrict__ h0,
    const float* __restrict__ c0,
    float* ys1, float* ys2,
    float* out)
{
    const int  w   = blockIdx.x & 7;
    const bool isL2 = blockIdx.x >= 8;
    const int  tid = threadIdx.x;
    const int  q   = tid & 7;
    const int  r   = tid >> 3;
    const int  chunk = r >> 5;
    const int  elem  = r & 31;
    const int  grow  = chunk * 256 + w * 32 + elem;
    const int  layer = isL2 ? 1 : 0;

    __shared__ __align__(16) float h_lds[HDIM];
    __shared__ __align__(16) float x_lds[HDIM];
    __shared__ float gate_lds[128];
    __shared__ float c_lds[32];

    // per-thread weight slices (32 floats each) — kept in VGPRs
    float whh[32];
    float wih[32];
    {
        const float4* p = (const float4*)((isL2 ? Whh1 : Whh0) + (size_t)grow * HDIM + q * 32);
        #pragma unroll
        for (int j = 0; j < 8; j++) {
            float4 v = p[j];
            whh[4*j] = v.x; whh[4*j+1] = v.y; whh[4*j+2] = v.z; whh[4*j+3] = v.w;
        }
    }
    float bsum = 0.f;
    if (isL2) {
        const float4* p = (const float4*)(Wih1 + (size_t)grow * HDIM + q * 32);
        #pragma unroll
        for (int j = 0; j < 8; j++) {
            float4 v = p[j];
            wih[4*j] = v.x; wih[4*j+1] = v.y; wih[4*j+2] = v.z; wih[4*j+3] = v.w;
        }
        if (q == 0) bsum = b_ih1[grow] + b_hh1[grow];
    } else {
        #pragma unroll
        for (int j = 0; j < 32; j++) wih[j] = 0.f;
    }

    if (tid < HDIM) h_lds[tid] = h0[layer * HDIM + tid];
    if (tid < 32)   c_lds[tid] = c0[layer * HDIM + w * 32 + tid];
    __syncthreads();

    float* mailOut = isL2 ? ys2 : ys1;

    for (int t = 0; t < NB; t++) {
        // L1: prefetch precomputed x-gate value (overlaps the poll)
        float gval = bsum;
        if (!isL2 && q == 0) gval = G1[(size_t)t * GDIM + grow];

        // ---- fill h_lds (remote slices) and, for L2, x_lds = ys1[t] ----
        if (!isL2) {
            if (t > 0 && tid < HDIM && (tid >> 5) != w) {
                const unsigned* p = (const unsigned*)&ys1[(size_t)(t - 1) * HDIM + tid];
                unsigned v; int guard = 0;
                do {
                    v = __hip_atomic_load(p, __ATOMIC_RELAXED, __HIP_MEMORY_SCOPE_AGENT);
                } while (v == 0xFFFFFFFFu && ++guard < (1 << 22));
                h_lds[tid] = __uint_as_float(v);
            }
        } else {
            if (tid < HDIM) {          // waves 0..3: poll x-input ys1[t] (all remote)
                const unsigned* p = (const unsigned*)&ys1[(size_t)t * HDIM + tid];
                unsigned v; int guard = 0;
                do {
                    v = __hip_atomic_load(p, __ATOMIC_RELAXED, __HIP_MEMORY_SCOPE_AGENT);
                } while (v == 0xFFFFFFFFu && ++guard < (1 << 22));
                x_lds[tid] = __uint_as_float(v);
            } else if (tid >= 512 && tid < 512 + HDIM) {   // waves 8..11: poll h2(t-1)
                int j = tid - 512;
                if (t > 0 && (j >> 5) != w) {
                    const unsigned* p = (const unsigned*)&ys2[(size_t)(t - 1) * HDIM + j];
                    unsigned v; int guard = 0;
                    do {
                        v = __hip_atomic_load(p, __ATOMIC_RELAXED, __HIP_MEMORY_SCOPE_AGENT);
                    } while (v == 0xFFFFFFFFu && ++guard < (1 << 22));
                    h_lds[j] = __uint_as_float(v);
                }
            }
        }
        __syncthreads();               // barrier A: h_lds/x_lds complete

        // ---- matvec: this thread's 32-wide chunk of its gate row ----
        float a0 = 0.f, a1 = 0.f, a2 = 0.f, a3 = 0.f;
        {
            const float4* h4 = ((const float4*)h_lds) + q * 8;
            #pragma unroll
            for (int j = 0; j < 8; j++) {
                float4 hv = h4[j];
                if (j & 1) {
                    a2 += hv.x * whh[4*j] + hv.y * whh[4*j+1];
                    a3 += hv.z * whh[4*j+2] + hv.w * whh[4*j+3];
                } else {
                    a0 += hv.x * whh[4*j] + hv.y * whh[4*j+1];
                    a1 += hv.z * whh[4*j+2] + hv.w * whh[4*j+3];
                }
            }
            if (isL2) {
                const float4* x4 = ((const float4*)x_lds) + q * 8;
                #pragma unroll
                for (int j = 0; j < 8; j++) {
                    float4 xv = x4[j];
                    if (j & 1) {
                        a2 += xv.x * wih[4*j] + xv.y * wih[4*j+1];
                        a3 += xv.z * wih[4*j+2] + xv.w * wih[4*j+3];
                    } else {
                        a0 += xv.x * wih[4*j] + xv.y * wih[4*j+1];
                        a1 += xv.z * wih[4*j+2] + xv.w * wih[4*j+3];
                    }
                }
            }
        }
        float acc = (a0 + a1) + (a2 + a3) + gval;
        acc += __shfl_xor(acc, 1);
        acc += __shfl_xor(acc, 2);
        acc += __shfl_xor(acc, 4);
        if (q == 0) gate_lds[r] = acc;
        __syncthreads();               // barrier B: gate_lds ready, h/x_lds free

        // ---- gate nonlinearity + state update + publish (wave 0 only) ----
        if (tid < 32) {
            float gi = gate_lds[tid];
            float gf = gate_lds[32 + tid];
            float gg = gate_lds[64 + tid];
            float go = gate_lds[96 + tid];
            float ig = 1.f / (1.f + expf(-gi));
            float fg = 1.f / (1.f + expf(-gf));
            float og = 1.f / (1.f + expf(-go));
            float c  = fg * c_lds[tid] + ig * tanhf(gg);
            c_lds[tid] = c;
            float h  = og * tanhf(c);
            h_lds[w * 32 + tid] = h;   // own slice for next step (local)
            __hip_atomic_store(&mailOut[(size_t)t * HDIM + w * 32 + tid], h,
                               __ATOMIC_RELAXED, __HIP_MEMORY_SCOPE_AGENT);
            if (t == NB - 1) {
                out[1024 + layer * HDIM + w * 32 + tid] = h;   // hn
                out[1536 + layer * HDIM + w * 32 + tid] = c;   // cn
            }
        }
        // no loop-end barrier: next iteration's barrier A orders everything;
        // pollers overlap with the gate computation.
    }
}

// ---------------------------------------------------------------------------
// Kernel 4: fc head
// ---------------------------------------------------------------------------
__global__ __launch_bounds__(256) void fc_kernel(const float* __restrict__ ys2,
                                                 const float* __restrict__ fc_w,
                                                 const float* __restrict__ fc_b,
                                                 float* __restrict__ out) {
    const int row  = blockIdx.x * 4 + (threadIdx.x >> 6);
    const int lane = threadIdx.x & 63;
    float4 y = ((const float4*)(ys2 + (size_t)row * HDIM))[lane];
    float4 wv = ((const float4*)fc_w)[lane];
    float d = y.x * wv.x + y.y * wv.y + y.z * wv.z + y.w * wv.w;
    #pragma unroll
    for (int m = 1; m < 64; m <<= 1) d += __shfl_xor(d, m);
    if (lane == 0) out[row] = 1.f / (1.f + expf(-(d + fc_b[0])));
}

// ---------------------------------------------------------------------------
extern "C" void kernel_launch(void* const* d_in, const int* in_sizes, int n_in,
                              void* d_out, int out_size, void* d_ws, size_t ws_size,
                              hipStream_t stream) {
    const int*   x     = (const int*)  d_in[0];
    const float* h0    = (const float*)d_in[1];
    const float* c0    = (const float*)d_in[2];
    const float* emb   = (const float*)d_in[3];
    const float* w_ih0 = (const float*)d_in[4];
    const float* w_hh0 = (const float*)d_in[5];
    const float* b_ih0 = (const float*)d_in[6];
    const float* b_hh0 = (const float*)d_in[7];
    const float* w_ih1 = (const float*)d_in[8];
    const float* w_hh1 = (const float*)d_in[9];
    const float* b_ih1 = (const float*)d_in[10];
    const float* b_hh1 = (const float*)d_in[11];
    const float* fc_w  = (const float*)d_in[12];
    const float* fc_b  = (const float*)d_in[13];
    float* out = (float*)d_out;

    // workspace layout (floats)
    float* X   = (float*)d_ws;                  // 1024*903
    float* G1  = X + (size_t)NB * DIN;          // 1024*1024
    float* ys1 = G1 + (size_t)NB * GDIM;        // 1024*256
    float* ys2 = ys1 + (size_t)NB * HDIM;       // 1024*256

    // sentinel-fill both exchange buffers (0xFFFFFFFF = NaN, never produced)
    hipMemsetAsync(ys1, 0xFF, 2 * (size_t)NB * HDIM * sizeof(float), stream);

    conv_kernel<<<NB, 256, 0, stream>>>(x, emb, X);

    gemm_bias<<<dim3(16, 16), 256, 0, stream>>>(X, w_ih0, b_ih0, b_hh0, G1, DIN);

    lstm_fused<<<16, 1024, 0, stream>>>(G1, w_hh0, w_ih1, w_hh1, b_ih1, b_hh1,
                                        h0, c0, ys1, ys2, out);

    fc_kernel<<<NB / 4, 256, 0, stream>>>(ys2, fc_w, fc_b, out);
}